// Round 9
// baseline (222.425 us; speedup 1.0000x reference)
//
#include <hip/hip_runtime.h>
#include <math.h>

#define N_MEM   50000
#define P_TOT   4096
#define DDIM    256
#define HDIM    480
#define WDIM    640
#define THR2    0.01f
#define EPSF    1e-8f

// ---- spatial hash grid over the 50000 UNIFORM mem points (rounds 4-8 verified geometry)
// cell 0.6875m >= 2*RS: query radius window spans <=2 cells/dim (8 cells, 1 thread each;
// collapsed ranges -> duplicate cells -> idempotent). RS=0.15 covers the 0.1m match
// radius with margin >> fp slop; clamped-trunc cell map is monotone so every pair with
// d2<THR2 is tested -> tested-min == true min whenever matched.
#define GDIM    24
#define NCELL   13824
#define GORG    -8.25f
#define GINV    (1.0f/0.6875f)
#define GRS     0.15f

// fixed-capacity buckets (round-8 verified): Poisson lambda~3.62 => ~20 overflow
// entries total; exact overflow backstop preserves correctness regardless of CAP.
#define CAP     10
#define OCAP    50000

// K1: 16 query + 196 mem-bucket + 812 pure-copy blocks (copy at full BW, not 212-block
// latency-bound as in round 8)
#define QB1     16
#define MB1     196
#define NB1     1024
#define NTH1    (NB1 * 256L)       // 262144
#define NWV     784                // mem waves writing wave_inv (196*4)

// K2: sweep + copy
#define SWEEPB  128
#define COPYB   2048

// copy split (float2 units of the 6.4M-float2 desc copy): 45% K1 / 55% K2
#define ND2     6400000L
#define CS1     2880000L
#define PTS2    75000L             // mem_pts copy (float2), K2

typedef unsigned long long ull;

// monotone float->uint transform: a<b (float) <=> fsort(a)<fsort(b) (uint)
__device__ __forceinline__ unsigned fsort(float x) {
    unsigned b = __float_as_uint(x);
    return (b & 0x80000000u) ? ~b : (b | 0x80000000u);
}

__device__ __forceinline__ int cell1d(float x) {
    int c = (int)((x - GORG) * GINV);
    return min(max(c, 0), GDIM - 1);
}

// lane-consecutive coalesced float2 copy of [lo,hi), 4 independent streams in flight
__device__ __forceinline__ void copy2(const float2* __restrict__ s, float2* __restrict__ d,
                                      long lo, long hi, long g, long n)
{
    long i = lo + g;
    for (; i + 3*n < hi; i += 4*n) {
        float2 a = s[i], b = s[i+n], c = s[i+2*n], e = s[i+3*n];
        d[i] = a; d[i+n] = b; d[i+2*n] = c; d[i+3*n] = e;
    }
    for (; i < hi; i += n) d[i] = s[i];
}

// ---- workspace layout (round-8 proven envelope; widx/scan_out slots now unused) ----
#define WS_PTS      0         //  65536  float4[4096]
#define WS_FLAGS    65536     //  16384  int[4096]   (v bit only; m/u decoded locally)
#define WS_MINKEY   98304     //  32768  ull[4096]
#define WS_WAVEINV  131072    //   6272  ull[784]
#define WS_WINOVF   137360    // 200000  int[50000]  (overflow list)
#define WS_BUCKET   337360    // 276480  ushort[13824*10]
#define WS_MCNT     613840    //  55296  int[13824]   (memset 0)
#define WS_OCUR     669136    //      4  int          (memset 0)  -> end 669140

// ---------------- K1: pix2world + mem bucket build + dout[0] zero + copy A ----------
__global__ __launch_bounds__(256) void k_build(const float* __restrict__ points,
                                               const float* __restrict__ depth,
                                               const float* __restrict__ pose,
                                               const float* __restrict__ Kmat,
                                               const float* __restrict__ mem_pts,
                                               const float* __restrict__ mem_desc,
                                               float* __restrict__ dout,
                                               char* __restrict__ ws)
{
    float4* pts      = (float4*)(ws + WS_PTS);
    int* flags       = (int*)(ws + WS_FLAGS);
    ull* minkey      = (ull*)(ws + WS_MINKEY);
    ull* wave_inv    = (ull*)(ws + WS_WAVEINV);
    int* overflow    = (int*)(ws + WS_WINOVF);
    unsigned short* bucket = (unsigned short*)(ws + WS_BUCKET);
    int* mcnt        = (int*)(ws + WS_MCNT);
    int* ocur        = (int*)(ws + WS_OCUR);
    const float2* dsrc = (const float2*)mem_desc;
    float2* ddst = (float2*)(dout + 2 + (long)N_MEM * 3);

    int t = threadIdx.x, bid = blockIdx.x;
    long gid = (long)bid * 256 + t;

    if (bid == 0 && t == 0) dout[0] = 0.f;   // K3 accumulates base + matched-cos onto 0

    if (bid < QB1) {
        // ---- pix2world for query point p (rounds 0/4/5/8-verified arithmetic) ----
        int p = bid * 256 + t;
        minkey[p] = 0xFFFFFFFFFFFFFFFFULL;
        int b = p >> 9;
        const float* K = Kmat + b * 9;
        float a00=K[0],a01=K[1],a02=K[2],a10=K[3],a11=K[4],a12=K[5],a20=K[6],a21=K[7],a22=K[8];
        float det = a00*(a11*a22-a12*a21) - a01*(a10*a22-a12*a20) + a02*(a10*a21-a11*a20);
        float id = 1.0f/det;
        float i00=(a11*a22-a12*a21)*id, i01=(a02*a21-a01*a22)*id, i02=(a01*a12-a02*a11)*id;
        float i10=(a12*a20-a10*a22)*id, i11=(a00*a22-a02*a20)*id, i12=(a02*a10-a00*a12)*id;
        float i20=(a10*a21-a11*a20)*id, i21=(a01*a20-a00*a21)*id, i22=(a00*a11-a01*a10)*id;
        float u = points[p*2+0], v = points[p*2+1];
        float uc = fminf(fmaxf(u, 0.f), (float)WDIM - 1.001f);
        float vc = fminf(fmaxf(v, 0.f), (float)HDIM - 1.001f);
        float u0 = floorf(uc), v0 = floorf(vc);
        float du = uc - u0, dv = vc - v0;
        int u0i = (int)u0, v0i = (int)v0;
        const float* dm = depth + (size_t)b * HDIM * WDIM;
        float d00 = dm[v0i*WDIM + u0i];
        float d01 = dm[v0i*WDIM + u0i + 1];
        float d10 = dm[(v0i+1)*WDIM + u0i];
        float d11 = dm[(v0i+1)*WDIM + u0i + 1];
        float d = d00*(1.f-du)*(1.f-dv) + d01*du*(1.f-dv) + d10*(1.f-du)*dv + d11*du*dv;
        float cx = (i00*u + i01*v + i02) * d;
        float cy = (i10*u + i11*v + i12) * d;
        float cz = (i20*u + i21*v + i22) * d;
        const float* T = pose + b * 12;
        float wx = T[0]*cx + T[1]*cy + T[2]*cz  + T[3];
        float wy = T[4]*cx + T[5]*cy + T[6]*cz  + T[7];
        float wz = T[8]*cx + T[9]*cy + T[10]*cz + T[11];
        int val = (d > 0.f) && isfinite(wx) && isfinite(wy) && isfinite(wz);
        float px = val ? wx : 1e6f;
        float py = val ? wy : 1e6f;
        float pz = val ? wz : 1e6f;
        float pp = px*px + py*py + pz*pz;    // same arith chain as prior passing kernels
        pts[p] = make_float4(px, py, pz, pp);
        flags[p] = val;
    } else if (bid < QB1 + MB1) {
        // ---- mem bucket build (1 iter/thread) + per-wave invalid-argmin ----
        int j = (bid - QB1) * 256 + t;
        ull wk = 0xFFFFFFFFFFFFFFFFULL;
        if (j < N_MEM) {
            float mx = mem_pts[j*3+0], my = mem_pts[j*3+1], mz = mem_pts[j*3+2];
            int c = (cell1d(mz) * GDIM + cell1d(my)) * GDIM + cell1d(mx);
            int pos = atomicAdd(&mcnt[c], 1);
            if (pos < CAP) bucket[c * CAP + pos] = (unsigned short)j;
            else {
                int op = atomicAdd(ocur, 1);
                if (op < OCAP) overflow[op] = j;
            }
            float mm = mx*mx + my*my + mz*mz;      // same expr as prior passing kernels
            float qx = 1e6f;
            float qp  = qx*qx + qx*qx + qx*qx;
            float dot = qx*mx + qx*my + qx*mz;
            float dinv = qp - 2.f*dot + mm;
            wk = ((ull)fsort(dinv) << 32) | (unsigned)j;   // (d, j) lexicographic
        }
        #pragma unroll
        for (int off = 32; off; off >>= 1) {
            ull o = __shfl_xor(wk, off);
            wk = o < wk ? o : wk;
        }
        if ((t & 63) == 0) wave_inv[((bid - QB1) * 256 + t) >> 6] = wk;
    }
    // all 1024 blocks: copy slice A (45%) at full BW
    copy2(dsrc, ddst, 0, CS1, gid, NTH1);
}

// ---------------- K2: query-side sweep (buckets + overflow) + copy B + pts copy -------
__global__ __launch_bounds__(256) void k_main(const float* __restrict__ mem_pts,
                                              const float* __restrict__ mem_desc,
                                              float* __restrict__ dout,
                                              char* __restrict__ ws)
{
    float4* pts      = (float4*)(ws + WS_PTS);
    int* flags       = (int*)(ws + WS_FLAGS);
    ull* minkey      = (ull*)(ws + WS_MINKEY);
    int* overflow    = (int*)(ws + WS_WINOVF);
    unsigned short* bucket = (unsigned short*)(ws + WS_BUCKET);
    int* mcnt        = (int*)(ws + WS_MCNT);
    int* ocur        = (int*)(ws + WS_OCUR);
    float* out_pts = dout + 2;
    const float2* dsrc = (const float2*)mem_desc;
    float2* ddst = (float2*)(dout + 2 + (long)N_MEM * 3);

    int bid = blockIdx.x, t = threadIdx.x;
    if (bid < SWEEPB) {
        int gid = bid * 256 + t;
        int p  = gid >> 3;
        int ci = gid & 7;
        if (!flags[p]) return;              // invalid: K3 substitutes the global argmin
        float4 P = pts[p];                  // 8 threads same addr: broadcast
        int x0 = cell1d(P.x - GRS), x1 = cell1d(P.x + GRS);
        int y0 = cell1d(P.y - GRS), y1 = cell1d(P.y + GRS);
        int z0 = cell1d(P.z - GRS), z1 = cell1d(P.z + GRS);
        int xx = (ci & 1)        ? x1 : x0; // duplicates when range collapsed: idempotent
        int yy = ((ci >> 1) & 1) ? y1 : y0;
        int zz = (ci >> 2)       ? z1 : z0;
        int cell = (zz * GDIM + yy) * GDIM + xx;
        int cnt = min(mcnt[cell], CAP);
        int base = cell * CAP;
        ull best = 0xFFFFFFFFFFFFFFFFULL;
        for (int k = 0; k < cnt; ++k) {
            int j = (int)bucket[base + k];
            float mx = mem_pts[j*3+0], my = mem_pts[j*3+1], mz = mem_pts[j*3+2];
            float mm  = mx*mx + my*my + mz*mz;
            float dot = P.x*mx + P.y*my + P.z*mz;
            float dd2 = P.w - 2.f*dot + mm;     // fp form identical to ref-passing kernels
            ull key = ((ull)fsort(dd2) << 32) | (unsigned)j;
            best = key < best ? key : best;
        }
        if (ci == 0) {                          // exact overflow backstop (~20 entries)
            int nov = min(*ocur, OCAP);
            for (int k = 0; k < nov; ++k) {
                int j = overflow[k];
                float mx = mem_pts[j*3+0], my = mem_pts[j*3+1], mz = mem_pts[j*3+2];
                float mm  = mx*mx + my*my + mz*mz;
                float dot = P.x*mx + P.y*my + P.z*mz;
                float dd2 = P.w - 2.f*dot + mm;
                ull key = ((ull)fsort(dd2) << 32) | (unsigned)j;
                best = key < best ? key : best;
            }
        }
        if (best != 0xFFFFFFFFFFFFFFFFULL)
            atomicMin(&minkey[p], best);        // exact (d, j) lexicographic min
    } else {
        const long tid = (long)(bid - SWEEPB) * 256 + t;
        const long NT = (long)COPYB * 256;
        copy2(dsrc, ddst, CS1, ND2, tid, NT);
        const float2* ps = (const float2*)mem_pts;
        float2* pd = (float2*)out_pts;
        for (long i = tid; i < PTS2; i += NT) pd[i] = ps[i];
    }
}

// ---------------- K3: scatloss with block-local scan (replaces old K3+K4) -------------
// Every block redundantly recomputes the deterministic decode/prefix/widx for all 4096
// points from minkey/flags (final after K2; ~55KB L2-hot) into LDS, derives its own
// widx[p], and computes winner = max{p' : widx[p']==wi} from LDS (stride-256,
// conflict-free). Loss = 0 (K1) + [block0: 1 - n_u/nv] + sum_matched(-cosv/nv) --
// all commuting atomicAdds, no fence/election (round-2 lesson).
__global__ __launch_bounds__(256) void k_scatloss(const float* __restrict__ desc,
                                                  const float* __restrict__ mem_pts,
                                                  const float* __restrict__ mem_desc,
                                                  const int* __restrict__ next_ptr,
                                                  float* __restrict__ dout,
                                                  char* __restrict__ ws)
{
    float4* pts     = (float4*)(ws + WS_PTS);
    int* flags      = (int*)(ws + WS_FLAGS);
    ull* minkey     = (ull*)(ws + WS_MINKEY);
    ull* wave_inv   = (ull*)(ws + WS_WAVEINV);
    float* out_pts  = dout + 2;
    float* out_desc = dout + 2 + (long)N_MEM * 3;

    __shared__ int wlds[P_TOT];     // packed: widx(16b) | v<<16 | m<<17 | u<<18
    __shared__ int su[256];
    __shared__ int smc[256];
    __shared__ ull ired[5];
    __shared__ float red[16];
    __shared__ int wmax[4];

    int p = blockIdx.x, t = threadIdx.x, lane = t & 63;

    // 1. reduce the 784 per-wave invalid-argmin keys
    ull ik = 0xFFFFFFFFFFFFFFFFULL;
    for (int w = t; w < NWV; w += 256) { ull v2 = wave_inv[w]; ik = v2 < ik ? v2 : ik; }
    #pragma unroll
    for (int off = 32; off; off >>= 1) {
        ull o = __shfl_xor(ik, off);
        ik = o < ik ? o : ik;
    }
    if (lane == 0) ired[t >> 6] = ik;
    __syncthreads();
    if (t == 0) {
        ull a = ired[0] < ired[1] ? ired[0] : ired[1];
        ull b = ired[2] < ired[3] ? ired[2] : ired[3];
        ired[4] = a < b ? a : b;
    }
    __syncthreads();
    ull inv = ired[4];

    // 2. decode 16 points/thread (identical semantics to round-8 K3)
    int base = t * 16;
    const ull thr_key = ((ull)fsort(THR2)) << 32;   // key<thr_key <=> d<THR2 exactly
    int pk[16];
    unsigned um_bits = 0;
    int usum = 0, msum = 0;
    #pragma unroll
    for (int k = 0; k < 16; k++) {
        int v = flags[base + k] & 1;
        ull key = v ? minkey[base + k] : inv;
        int m = (key < thr_key) && v;
        int u = (!m) && v;
        int iv = (int)(key & 0xffffffffULL);        // < 50000 < 2^16
        um_bits |= ((unsigned)u) << k;
        usum += u; msum += m;
        pk[k] = (v << 16) | (m << 17) | (u << 18) | (u ? 0 : iv);
    }
    su[t] = usum; smc[t] = msum;
    __syncthreads();
    for (int off = 1; off < 256; off <<= 1) {
        int a = su[t], b = (t >= off) ? su[t - off] : 0;
        int c = smc[t], d = (t >= off) ? smc[t - off] : 0;
        __syncthreads();
        su[t] = a + b; smc[t] = c + d;
        __syncthreads();
    }
    int excl = su[t] - usum;
    int np_ = *next_ptr;
    int run = excl;
    #pragma unroll
    for (int k = 0; k < 16; k++) {
        if ((um_bits >> k) & 1) { run += 1; pk[k] |= (np_ + run - 1) % N_MEM; }
        wlds[base + k] = pk[k];
    }
    __syncthreads();

    // 3. own point + winner (max p' with widx==wi; LDS stride-256, 2 lanes/bank = free)
    int mypk = wlds[p];
    int wi = mypk & 0xFFFF;
    int m = (mypk >> 17) & 1, u = (mypk >> 18) & 1;
    float nvf = fmaxf((float)(su[255] + smc[255]), 1.f);
    int best = -1;
    for (int k = t; k < P_TOT; k += 256)
        if ((wlds[k] & 0xFFFF) == wi) best = k;     // ascending -> last hit = thread max
    #pragma unroll
    for (int off = 32; off; off >>= 1) {
        int o = __shfl_xor(best, off);
        best = o > best ? o : best;
    }
    if (lane == 0) wmax[t >> 6] = best;
    __syncthreads();
    int winp = max(max(wmax[0], wmax[1]), max(wmax[2], wmax[3]));
    int win = (winp == p);

    // 4. block 0: n_match + loss base (dout[0] zeroed by K1; all adds commute)
    if (p == 0 && t == 0) {
        dout[1] = (float)smc[255];
        atomicAdd(&dout[0], 1.f - (float)su[255] / nvf);
    }

    if (!m && !win) return;                 // block-uniform early exit
    // 5. EMA/cos (round-4/5/8-verified math)
    float dsg = desc[p * DDIM + t];
    float old = mem_desc[(long)wi * DDIM + t];   // for matched, wi == idx[p]
    float val;
    if (m) {
        float up = old * 0.5f + dsg * 0.5f;
        float sdd = dsg * dsg, smm2 = old * old, sdm = dsg * old, suu = up * up;
        #pragma unroll
        for (int off = 32; off; off >>= 1) {
            sdd  += __shfl_xor(sdd,  off);
            smm2 += __shfl_xor(smm2, off);
            sdm  += __shfl_xor(sdm,  off);
            suu  += __shfl_xor(suu,  off);
        }
        int w = t >> 6;
        if ((t & 63) == 0) { red[w] = sdd; red[4+w] = smm2; red[8+w] = sdm; red[12+w] = suu; }
        __syncthreads();
        float dd  = red[0] + red[1] + red[2] + red[3];
        float mm2 = red[4] + red[5] + red[6] + red[7];
        float dm  = red[8] + red[9] + red[10] + red[11];
        float uu  = red[12] + red[13] + red[14] + red[15];
        float cosv = dm / (fmaxf(sqrtf(dd), EPSF) * fmaxf(sqrtf(mm2), EPSF));
        val = up / (sqrtf(uu) + EPSF);
        if (t == 0) atomicAdd(&dout[0], -cosv / nvf);
    } else {
        val = u ? dsg : old;                // invalid winner rewrites old value
    }
    if (win) {
        out_desc[(long)wi * DDIM + t] = val;
        if (t == 0) {
            float px, py, pz;
            if (u) { float4 P = pts[p]; px = P.x; py = P.y; pz = P.z; }
            else   { px = mem_pts[wi*3]; py = mem_pts[wi*3+1]; pz = mem_pts[wi*3+2]; }
            out_pts[wi*3+0] = px; out_pts[wi*3+1] = py; out_pts[wi*3+2] = pz;
        }
    }
}

extern "C" void kernel_launch(void* const* d_in, const int* in_sizes, int n_in,
                              void* d_out, int out_size, void* d_ws, size_t ws_size,
                              hipStream_t stream)
{
    const float* points   = (const float*)d_in[0];
    const float* depth    = (const float*)d_in[1];
    const float* pose     = (const float*)d_in[2];
    const float* Kmat     = (const float*)d_in[3];
    const float* desc     = (const float*)d_in[4];
    const float* mem_pts  = (const float*)d_in[5];
    const float* mem_desc = (const float*)d_in[6];
    const int*   next_ptr = (const int*)d_in[7];
    float* out = (float*)d_out;
    char* ws = (char*)d_ws;

    // zero cell counts + overflow cursor (55300 B)
    hipMemsetAsync(ws + WS_MCNT, 0, 55300, stream);
    k_build   <<<NB1, 256, 0, stream>>>(points, depth, pose, Kmat, mem_pts, mem_desc,
                                        out, ws);
    k_main    <<<SWEEPB + COPYB, 256, 0, stream>>>(mem_pts, mem_desc, out, ws);
    k_scatloss<<<P_TOT, 256, 0, stream>>>(desc, mem_pts, mem_desc, next_ptr, out, ws);
}

// Round 10
// 165.831 us; speedup vs baseline: 1.3413x; 1.3413x over previous
//
#include <hip/hip_runtime.h>
#include <math.h>

#define N_MEM   50000
#define P_TOT   4096
#define DDIM    256
#define HDIM    480
#define WDIM    640
#define THR2    0.01f
#define EPSF    1e-8f

// ---- spatial hash grid over the 50000 UNIFORM mem points (rounds 4-9 verified geometry)
// cell 0.6875m >= 2*RS: query radius window spans <=2 cells/dim (8 cells, 1 thread each;
// collapsed ranges -> duplicate cells -> idempotent). RS=0.15 covers the 0.1m match
// radius with margin >> fp slop; clamped-trunc cell map is monotone so every pair with
// d2<THR2 is tested -> tested-min == true min whenever matched.
#define GDIM    24
#define NCELL   13824
#define GORG    -8.25f
#define GINV    (1.0f/0.6875f)
#define GRS     0.15f

// fixed-capacity buckets (round-8 verified): Poisson lambda~3.62 => ~20 overflow
// entries total; exact overflow backstop preserves correctness regardless of CAP.
#define CAP     10
#define OCAP    50000

// K1: 16 query + 196 mem-bucket + 812 pure-copy blocks (round-9 improvement kept:
// copy leg at full BW; round-8's 212-block copy was latency-bound)
#define QB1     16
#define MB1     196
#define NB1     1024
#define NTH1    (NB1 * 256L)       // 262144
#define NWV     784                // mem waves writing wave_inv (196*4)

// K2: sweep + copy
#define SWEEPB  128
#define COPYB   2048

// copy split (float2 units of the 6.4M-float2 desc copy): 45% K1 / 55% K2
#define ND2     6400000L
#define CS1     2880000L
#define PTS2    75000L             // mem_pts copy (float2), K2

typedef unsigned long long ull;

// monotone float->uint transform: a<b (float) <=> fsort(a)<fsort(b) (uint)
__device__ __forceinline__ unsigned fsort(float x) {
    unsigned b = __float_as_uint(x);
    return (b & 0x80000000u) ? ~b : (b | 0x80000000u);
}

__device__ __forceinline__ int cell1d(float x) {
    int c = (int)((x - GORG) * GINV);
    return min(max(c, 0), GDIM - 1);
}

// lane-consecutive coalesced float2 copy of [lo,hi), 4 independent streams in flight
__device__ __forceinline__ void copy2(const float2* __restrict__ s, float2* __restrict__ d,
                                      long lo, long hi, long g, long n)
{
    long i = lo + g;
    for (; i + 3*n < hi; i += 4*n) {
        float2 a = s[i], b = s[i+n], c = s[i+2*n], e = s[i+3*n];
        d[i] = a; d[i+n] = b; d[i+2*n] = c; d[i+3*n] = e;
    }
    for (; i < hi; i += n) d[i] = s[i];
}

// ---- workspace layout (round-8 proven envelope, 669,140 B total) ----
#define WS_PTS      0         //  65536  float4[4096]
#define WS_FLAGS    65536     //  16384  int[4096]
#define WS_WIDX     81920     //  16384  int[4096]
#define WS_MINKEY   98304     //  32768  ull[4096]
#define WS_WAVEINV  131072    //   6272  ull[784]
#define WS_SCANOUT  137344    //     16  float[4]
#define WS_WINOVF   137360    // 200000  int[50000] (overflow in K1/K2, winner in K3/K4)
#define WS_BUCKET   337360    // 276480  ushort[13824*10]
#define WS_MCNT     613840    //  55296  int[13824]   (memset 0)
#define WS_OCUR     669136    //      4  int          (memset 0)  -> end 669140

// ---------------- K1: pix2world (16) + mem bucket build (196) + copy A (all 1024) ----
__global__ __launch_bounds__(256) void k_build(const float* __restrict__ points,
                                               const float* __restrict__ depth,
                                               const float* __restrict__ pose,
                                               const float* __restrict__ Kmat,
                                               const float* __restrict__ mem_pts,
                                               const float* __restrict__ mem_desc,
                                               float* __restrict__ dout,
                                               char* __restrict__ ws)
{
    float4* pts      = (float4*)(ws + WS_PTS);
    int* flags       = (int*)(ws + WS_FLAGS);
    ull* minkey      = (ull*)(ws + WS_MINKEY);
    ull* wave_inv    = (ull*)(ws + WS_WAVEINV);
    int* overflow    = (int*)(ws + WS_WINOVF);
    unsigned short* bucket = (unsigned short*)(ws + WS_BUCKET);
    int* mcnt        = (int*)(ws + WS_MCNT);
    int* ocur        = (int*)(ws + WS_OCUR);
    const float2* dsrc = (const float2*)mem_desc;
    float2* ddst = (float2*)(dout + 2 + (long)N_MEM * 3);

    int t = threadIdx.x, bid = blockIdx.x;
    long gid = (long)bid * 256 + t;

    if (bid < QB1) {
        // ---- pix2world for query point p (rounds 0/4/5/8-verified arithmetic) ----
        int p = bid * 256 + t;
        minkey[p] = 0xFFFFFFFFFFFFFFFFULL;
        int b = p >> 9;
        const float* K = Kmat + b * 9;
        float a00=K[0],a01=K[1],a02=K[2],a10=K[3],a11=K[4],a12=K[5],a20=K[6],a21=K[7],a22=K[8];
        float det = a00*(a11*a22-a12*a21) - a01*(a10*a22-a12*a20) + a02*(a10*a21-a11*a20);
        float id = 1.0f/det;
        float i00=(a11*a22-a12*a21)*id, i01=(a02*a21-a01*a22)*id, i02=(a01*a12-a02*a11)*id;
        float i10=(a12*a20-a10*a22)*id, i11=(a00*a22-a02*a20)*id, i12=(a02*a10-a00*a12)*id;
        float i20=(a10*a21-a11*a20)*id, i21=(a01*a20-a00*a21)*id, i22=(a00*a11-a01*a10)*id;
        float u = points[p*2+0], v = points[p*2+1];
        float uc = fminf(fmaxf(u, 0.f), (float)WDIM - 1.001f);
        float vc = fminf(fmaxf(v, 0.f), (float)HDIM - 1.001f);
        float u0 = floorf(uc), v0 = floorf(vc);
        float du = uc - u0, dv = vc - v0;
        int u0i = (int)u0, v0i = (int)v0;
        const float* dm = depth + (size_t)b * HDIM * WDIM;
        float d00 = dm[v0i*WDIM + u0i];
        float d01 = dm[v0i*WDIM + u0i + 1];
        float d10 = dm[(v0i+1)*WDIM + u0i];
        float d11 = dm[(v0i+1)*WDIM + u0i + 1];
        float d = d00*(1.f-du)*(1.f-dv) + d01*du*(1.f-dv) + d10*(1.f-du)*dv + d11*du*dv;
        float cx = (i00*u + i01*v + i02) * d;
        float cy = (i10*u + i11*v + i12) * d;
        float cz = (i20*u + i21*v + i22) * d;
        const float* T = pose + b * 12;
        float wx = T[0]*cx + T[1]*cy + T[2]*cz  + T[3];
        float wy = T[4]*cx + T[5]*cy + T[6]*cz  + T[7];
        float wz = T[8]*cx + T[9]*cy + T[10]*cz + T[11];
        int val = (d > 0.f) && isfinite(wx) && isfinite(wy) && isfinite(wz);
        float px = val ? wx : 1e6f;
        float py = val ? wy : 1e6f;
        float pz = val ? wz : 1e6f;
        float pp = px*px + py*py + pz*pz;    // same arith chain as prior passing kernels
        pts[p] = make_float4(px, py, pz, pp);
        flags[p] = val;
    } else if (bid < QB1 + MB1) {
        // ---- mem bucket build (1 iter/thread) + per-wave invalid-argmin ----
        int j = (bid - QB1) * 256 + t;
        ull wk = 0xFFFFFFFFFFFFFFFFULL;
        if (j < N_MEM) {
            float mx = mem_pts[j*3+0], my = mem_pts[j*3+1], mz = mem_pts[j*3+2];
            int c = (cell1d(mz) * GDIM + cell1d(my)) * GDIM + cell1d(mx);
            int pos = atomicAdd(&mcnt[c], 1);
            if (pos < CAP) bucket[c * CAP + pos] = (unsigned short)j;
            else {
                int op = atomicAdd(ocur, 1);
                if (op < OCAP) overflow[op] = j;
            }
            float mm = mx*mx + my*my + mz*mz;      // same expr as prior passing kernels
            float qx = 1e6f;
            float qp  = qx*qx + qx*qx + qx*qx;
            float dot = qx*mx + qx*my + qx*mz;
            float dinv = qp - 2.f*dot + mm;
            wk = ((ull)fsort(dinv) << 32) | (unsigned)j;   // (d, j) lexicographic
        }
        #pragma unroll
        for (int off = 32; off; off >>= 1) {
            ull o = __shfl_xor(wk, off);
            wk = o < wk ? o : wk;
        }
        if ((t & 63) == 0) wave_inv[((bid - QB1) * 256 + t) >> 6] = wk;
    }
    // all 1024 blocks: copy slice A (45%) at full BW
    copy2(dsrc, ddst, 0, CS1, gid, NTH1);
}

// ---------------- K2: query-side sweep (buckets + overflow) + copy B + pts copy -------
__global__ __launch_bounds__(256) void k_main(const float* __restrict__ mem_pts,
                                              const float* __restrict__ mem_desc,
                                              float* __restrict__ dout,
                                              char* __restrict__ ws)
{
    float4* pts      = (float4*)(ws + WS_PTS);
    int* flags       = (int*)(ws + WS_FLAGS);
    ull* minkey      = (ull*)(ws + WS_MINKEY);
    int* overflow    = (int*)(ws + WS_WINOVF);
    unsigned short* bucket = (unsigned short*)(ws + WS_BUCKET);
    int* mcnt        = (int*)(ws + WS_MCNT);
    int* ocur        = (int*)(ws + WS_OCUR);
    float* out_pts = dout + 2;
    const float2* dsrc = (const float2*)mem_desc;
    float2* ddst = (float2*)(dout + 2 + (long)N_MEM * 3);

    int bid = blockIdx.x, t = threadIdx.x;
    if (bid < SWEEPB) {
        int gid = bid * 256 + t;
        int p  = gid >> 3;
        int ci = gid & 7;
        if (!flags[p]) return;              // invalid: K3 substitutes the global argmin
        float4 P = pts[p];                  // 8 threads same addr: broadcast
        int x0 = cell1d(P.x - GRS), x1 = cell1d(P.x + GRS);
        int y0 = cell1d(P.y - GRS), y1 = cell1d(P.y + GRS);
        int z0 = cell1d(P.z - GRS), z1 = cell1d(P.z + GRS);
        int xx = (ci & 1)        ? x1 : x0; // duplicates when range collapsed: idempotent
        int yy = ((ci >> 1) & 1) ? y1 : y0;
        int zz = (ci >> 2)       ? z1 : z0;
        int cell = (zz * GDIM + yy) * GDIM + xx;
        int cnt = min(mcnt[cell], CAP);
        int base = cell * CAP;
        ull best = 0xFFFFFFFFFFFFFFFFULL;
        for (int k = 0; k < cnt; ++k) {
            int j = (int)bucket[base + k];
            float mx = mem_pts[j*3+0], my = mem_pts[j*3+1], mz = mem_pts[j*3+2];
            float mm  = mx*mx + my*my + mz*mz;
            float dot = P.x*mx + P.y*my + P.z*mz;
            float dd2 = P.w - 2.f*dot + mm;     // fp form identical to ref-passing kernels
            ull key = ((ull)fsort(dd2) << 32) | (unsigned)j;
            best = key < best ? key : best;
        }
        if (ci == 0) {                          // exact overflow backstop (~20 entries)
            int nov = min(*ocur, OCAP);
            for (int k = 0; k < nov; ++k) {
                int j = overflow[k];
                float mx = mem_pts[j*3+0], my = mem_pts[j*3+1], mz = mem_pts[j*3+2];
                float mm  = mx*mx + my*my + mz*mz;
                float dot = P.x*mx + P.y*my + P.z*mz;
                float dd2 = P.w - 2.f*dot + mm;
                ull key = ((ull)fsort(dd2) << 32) | (unsigned)j;
                best = key < best ? key : best;
            }
        }
        if (best != 0xFFFFFFFFFFFFFFFFULL)
            atomicMin(&minkey[p], best);        // exact (d, j) lexicographic min
    } else {
        const long tid = (long)(bid - SWEEPB) * 256 + t;
        const long NT = (long)COPYB * 256;
        copy2(dsrc, ddst, CS1, ND2, tid, NT);
        const float2* ps = (const float2*)mem_pts;
        float2* pd = (float2*)out_pts;
        for (long i = tid; i < PTS2; i += NT) pd[i] = ps[i];
    }
}

// ---------------- K3: wave_inv reduce + decode/scan -> widx, winner, loss base --------
// (round-8-verified; single 1024-thread block, global-scan ONCE -- the round-9
//  per-block redundant variant cost 79us in LDS bank conflicts, reverted)
__global__ __launch_bounds__(1024) void k_scan(const int* __restrict__ next_ptr,
                                               float* __restrict__ dout,
                                               char* __restrict__ ws)
{
    int* flags      = (int*)(ws + WS_FLAGS);
    int* widx       = (int*)(ws + WS_WIDX);
    ull* minkey     = (ull*)(ws + WS_MINKEY);
    ull* wave_inv   = (ull*)(ws + WS_WAVEINV);
    float* scan_out = (float*)(ws + WS_SCANOUT);
    int* winner     = (int*)(ws + WS_WINOVF);    // overflow region repurposed

    __shared__ int su[1024];
    __shared__ int smc[1024];
    __shared__ ull ired[17];
    int t = threadIdx.x;
    int lane = t & 63;

    // reduce the 784 per-wave invalid-argmin keys
    ull ik = (t < NWV) ? wave_inv[t] : 0xFFFFFFFFFFFFFFFFULL;
    #pragma unroll
    for (int off = 32; off; off >>= 1) {
        ull o = __shfl_xor(ik, off);
        ik = o < ik ? o : ik;
    }
    if (lane == 0) ired[t >> 6] = ik;
    __syncthreads();
    if (t == 0) {
        ull m = ired[0];
        for (int w = 1; w < 16; ++w) m = ired[w] < m ? ired[w] : m;
        ired[16] = m;
    }
    __syncthreads();
    ull inv = ired[16];

    int base = t * 4;
    const ull thr_key = ((ull)fsort(THR2)) << 32;   // key<thr_key <=> d<THR2 exactly
    int um[4], iv[4], wvv[4];
    int usum = 0, msum = 0;
    #pragma unroll
    for (int k = 0; k < 4; k++) {
        int v = flags[base + k] & 1;
        ull key = v ? minkey[base + k] : inv;
        int m = (key < thr_key) && v;
        int u = (!m) && v;
        iv[k] = (int)(key & 0xffffffffULL);
        um[k] = u; usum += u; msum += m;
        flags[base + k] = v | (m << 1) | (u << 2);
    }
    su[t] = usum; smc[t] = msum;
    __syncthreads();
    for (int off = 1; off < 1024; off <<= 1) {
        int a = su[t], b = (t >= off) ? su[t - off] : 0;
        int c = smc[t], d = (t >= off) ? smc[t - off] : 0;
        __syncthreads();
        su[t] = a + b; smc[t] = c + d;
        __syncthreads();
    }
    int excl = su[t] - usum;
    int np_ = *next_ptr;
    int run = excl;
    #pragma unroll
    for (int k = 0; k < 4; k++) {
        int wv;
        if (um[k]) { run += 1; wv = (np_ + run - 1) % N_MEM; }
        else       { wv = iv[k]; }
        widx[base + k] = wv;
        wvv[k] = wv;
        winner[wv] = -1;                   // init touched slots (racing -1 stores benign)
    }
    __syncthreads();
    #pragma unroll
    for (int k = 0; k < 4; k++)
        atomicMax(&winner[wvv[k]], base + k);   // last-write-wins = max p per slot
    if (t == 1023) {
        int n_u = su[1023];
        float nvf = fmaxf((float)(smc[1023] + n_u), 1.f);
        dout[1]     = (float)smc[1023];                // n_match
        dout[0]     = 1.f - (float)n_u / nvf;          // loss base; K4 adds -cosv/nv
        scan_out[0] = nvf;
    }
}

// ---------------- K4: scatter-update + matched-cos accumulation into dout[0] ----------
__global__ __launch_bounds__(256) void k_scatloss(const float* __restrict__ desc,
                                                  const float* __restrict__ mem_pts,
                                                  const float* __restrict__ mem_desc,
                                                  float* __restrict__ dout,
                                                  char* __restrict__ ws)
{
    float4* pts     = (float4*)(ws + WS_PTS);
    int* flags      = (int*)(ws + WS_FLAGS);
    int* widx       = (int*)(ws + WS_WIDX);
    float* scan_out = (float*)(ws + WS_SCANOUT);
    int* winner     = (int*)(ws + WS_WINOVF);
    float* out_pts  = dout + 2;
    float* out_desc = dout + 2 + (long)N_MEM * 3;

    __shared__ float red[16];
    int p = blockIdx.x;
    int t = threadIdx.x;
    int f = flags[p];
    int m = (f >> 1) & 1, u = (f >> 2) & 1;
    int wi = widx[p];
    int win = (winner[wi] == p);
    if (!m && !win) return;                 // block-uniform early exit
    float dsg = desc[p * DDIM + t];
    float old = mem_desc[(long)wi * DDIM + t];   // for matched, wi == idx[p]
    float val;
    if (m) {
        float up = old * 0.5f + dsg * 0.5f;
        float sdd = dsg * dsg, smm2 = old * old, sdm = dsg * old, suu = up * up;
        #pragma unroll
        for (int off = 32; off; off >>= 1) {
            sdd  += __shfl_xor(sdd,  off);
            smm2 += __shfl_xor(smm2, off);
            sdm  += __shfl_xor(sdm,  off);
            suu  += __shfl_xor(suu,  off);
        }
        int w = t >> 6;
        if ((t & 63) == 0) { red[w] = sdd; red[4+w] = smm2; red[8+w] = sdm; red[12+w] = suu; }
        __syncthreads();
        float dd  = red[0] + red[1] + red[2] + red[3];
        float mm2 = red[4] + red[5] + red[6] + red[7];
        float dm  = red[8] + red[9] + red[10] + red[11];
        float uu  = red[12] + red[13] + red[14] + red[15];
        float cosv = dm / (fmaxf(sqrtf(dd), EPSF) * fmaxf(sqrtf(mm2), EPSF));
        val = up / (sqrtf(uu) + EPSF);
        if (t == 0) atomicAdd(&dout[0], -cosv / scan_out[0]);
    } else {
        val = u ? dsg : old;                // invalid winner rewrites old value
    }
    if (win) {
        out_desc[(long)wi * DDIM + t] = val;
        if (t == 0) {
            float px, py, pz;
            if (u) { float4 P = pts[p]; px = P.x; py = P.y; pz = P.z; }
            else   { px = mem_pts[wi*3]; py = mem_pts[wi*3+1]; pz = mem_pts[wi*3+2]; }
            out_pts[wi*3+0] = px; out_pts[wi*3+1] = py; out_pts[wi*3+2] = pz;
        }
    }
}

extern "C" void kernel_launch(void* const* d_in, const int* in_sizes, int n_in,
                              void* d_out, int out_size, void* d_ws, size_t ws_size,
                              hipStream_t stream)
{
    const float* points   = (const float*)d_in[0];
    const float* depth    = (const float*)d_in[1];
    const float* pose     = (const float*)d_in[2];
    const float* Kmat     = (const float*)d_in[3];
    const float* desc     = (const float*)d_in[4];
    const float* mem_pts  = (const float*)d_in[5];
    const float* mem_desc = (const float*)d_in[6];
    const int*   next_ptr = (const int*)d_in[7];
    float* out = (float*)d_out;
    char* ws = (char*)d_ws;

    // zero cell counts + overflow cursor (55300 B)
    hipMemsetAsync(ws + WS_MCNT, 0, 55300, stream);
    k_build   <<<NB1, 256, 0, stream>>>(points, depth, pose, Kmat, mem_pts, mem_desc,
                                        out, ws);
    k_main    <<<SWEEPB + COPYB, 256, 0, stream>>>(mem_pts, mem_desc, out, ws);
    k_scan    <<<1, 1024, 0, stream>>>(next_ptr, out, ws);
    k_scatloss<<<P_TOT, 256, 0, stream>>>(desc, mem_pts, mem_desc, out, ws);
}